// Round 15
// baseline (344.075 us; speedup 1.0000x reference)
//
#include <hip/hip_runtime.h>
#include <math.h>

#define NNODES 50000
#define NEDGES 800000
#define GB 782  // gemm1 row-blocks = (NNODES+63)/64

typedef _Float16 f16;
typedef _Float16 f16x8 __attribute__((ext_vector_type(8)));
typedef _Float16 f16x4 __attribute__((ext_vector_type(4)));
typedef float f32x4 __attribute__((ext_vector_type(4)));
typedef float f32x8 __attribute__((ext_vector_type(8)));

// ---------------- CSR build + weight pack ----------------

// blocks [0,3125): degree histogram; blocks [3125,3285): weight fragment pack
__global__ __launch_bounds__(256) void k_deg_wfrag(const int* __restrict__ ei, int* __restrict__ deg,
                                                   const float* __restrict__ W1, const float* __restrict__ W2,
                                                   f16* __restrict__ W1f, f16* __restrict__ W2f) {
    int bid = blockIdx.x;
    if (bid < NEDGES / 256) {
        int e = bid * 256 + threadIdx.x;
        atomicAdd(&deg[ei[NEDGES + e]], 1);
    } else {
        int id = (bid - NEDGES / 256) * 256 + threadIdx.x;
        if (id < 32768) {  // W1: 128 x 256
            int k = id >> 8, c = id & 255;
            int kc = k >> 5, quad = (k & 31) >> 3, j = k & 7;
            W1f[(((kc << 8) + c) * 4 + quad) * 8 + j] = (f16)W1[id];
        } else {           // W2: 256 x 32
            int i2 = id - 32768;
            int k = i2 >> 5, c = i2 & 31;
            int kc = k >> 5, quad = (k & 31) >> 3, j = k & 7;
            W2f[(((kc << 5) + c) * 4 + quad) * 8 + j] = (f16)W2[i2];
        }
    }
}

__global__ __launch_bounds__(256) void k_scanA(const int* __restrict__ deg, int* __restrict__ incl,
                                               int* __restrict__ partial) {
    int t = threadIdx.x;
    int i = blockIdx.x * 256 + t;
    int v = (i < NNODES) ? deg[i] : 0;
    int lane = t & 63, wid = t >> 6;
    int s = v;
#pragma unroll
    for (int d = 1; d < 64; d <<= 1) { int u = __shfl_up(s, d, 64); if (lane >= d) s += u; }
    __shared__ int wtot[4];
    if (lane == 63) wtot[wid] = s;
    __syncthreads();
    int off = 0;
    for (int w = 0; w < wid; ++w) off += wtot[w];
    s += off;
    if (i < NNODES) incl[i] = s;
    if (t == 255) partial[blockIdx.x] = s;
}

__global__ __launch_bounds__(256) void k_scanC(const int* __restrict__ deg, const int* __restrict__ incl,
                                               const int* __restrict__ partial, int* __restrict__ rowst,
                                               int* __restrict__ cursor) {
    int t = threadIdx.x, bid = blockIdx.x;
    int v = (t < bid) ? partial[t] : 0;  // bid <= 195 < 256
    int lane = t & 63, wid = t >> 6;
#pragma unroll
    for (int d = 1; d < 64; d <<= 1) v += __shfl_xor(v, d);
    __shared__ int ws[4];
    if (lane == 0) ws[wid] = v;
    __syncthreads();
    int choff = ws[0] + ws[1] + ws[2] + ws[3];
    int i = bid * 256 + t;
    if (i < NNODES) {
        int rs1 = incl[i] + choff;
        rowst[i + 1] = rs1;
        cursor[i] = rs1 - deg[i];
        if (i == 0) rowst[0] = 0;
    }
}

// standalone thin scatter: sd_csr[pos] = (dst<<16)|src. 3.2-MB target region
// stays L2-resident when not competing with gemm streams (R12 lesson).
__global__ __launch_bounds__(256) void k_scatter(const int* __restrict__ ei, int* __restrict__ cursor,
                                                 unsigned* __restrict__ sd_csr) {
    int e = blockIdx.x * 256 + threadIdx.x;
    if (e >= NEDGES) return;
    int s = ei[e], d = ei[NEDGES + e];
    int pos = atomicAdd(&cursor[d], 1);
    sd_csr[pos] = ((unsigned)d << 16) | (unsigned)s;
}

// ---------------- gemm1 (R12 kernel verbatim; scatter branch dead at GB blocks) ----
// mfma_f32_16x16x32_f16 (lane=tid&63, r=lane&15, quad=lane>>4):
//   A frag a[j]=A[r][quad*8+j]  B frag b[j]=B[quad*8+j][r]  D d[i]=D[quad*4+i][r]

__global__ __launch_bounds__(256) void k_gemm1_sc(const float* __restrict__ X, const f16* __restrict__ W1f,
                                                  const float* __restrict__ Asrc, const float* __restrict__ Adst,
                                                  f16* __restrict__ h1h, float* __restrict__ as1,
                                                  float* __restrict__ ad1, const int* __restrict__ ei,
                                                  int* __restrict__ cursor, unsigned* __restrict__ sd_csr) {
    __shared__ f16 sA[64 * 136];
    int bid = blockIdx.x;
    int t = threadIdx.x;
    if (bid >= GB) {  // dead at GB-block launch; kept for binary parity with R12
        int e = (bid - GB) * 256 + t;
        if (e < NEDGES) {
            int s = ei[e], d = ei[NEDGES + e];
            int pos = atomicAdd(&cursor[d], 1);
            sd_csr[pos] = ((unsigned)d << 16) | (unsigned)s;
        }
        return;
    }
    int bm = bid * 64;
#pragma unroll
    for (int i = 0; i < 8; ++i) {
        int idx = i * 256 + t;
        int row = idx >> 5, c4 = (idx & 31) << 2;
        int gr = bm + row;
        float4 v = make_float4(0.f, 0.f, 0.f, 0.f);
        if (gr < NNODES) v = *(const float4*)(X + (size_t)gr * 128 + c4);
        f16x4 h = {(f16)v.x, (f16)v.y, (f16)v.z, (f16)v.w};
        *(f16x4*)&sA[row * 136 + c4] = h;
    }
    __syncthreads();
    int lane = t & 63, w = t >> 6;
    int r = lane & 15, quad = lane >> 4;
    int r0 = w * 16;
    f32x4 acc[2][8];
#pragma unroll
    for (int h2 = 0; h2 < 2; ++h2)
#pragma unroll
        for (int nt = 0; nt < 8; ++nt) acc[h2][nt] = (f32x4){0.f, 0.f, 0.f, 0.f};
#pragma unroll
    for (int kc = 0; kc < 4; ++kc) {
        f16x8 a = *(f16x8*)&sA[(r0 + r) * 136 + kc * 32 + quad * 8];
#pragma unroll
        for (int h2 = 0; h2 < 2; ++h2)
#pragma unroll
            for (int nt = 0; nt < 8; ++nt) {
                f16x8 b = *(const f16x8*)&W1f[(((kc << 8) + h2 * 128 + nt * 16 + r) * 4 + quad) * 8];
                acc[h2][nt] = __builtin_amdgcn_mfma_f32_16x16x32_f16(a, b, acc[h2][nt], 0, 0, 0);
            }
    }
#pragma unroll
    for (int h2 = 0; h2 < 2; ++h2)
#pragma unroll
        for (int nt = 0; nt < 8; ++nt)
#pragma unroll
            for (int i = 0; i < 4; ++i) {
                int gr = bm + r0 + quad * 4 + i;
                if (gr < NNODES) h1h[(size_t)gr * 256 + h2 * 128 + nt * 16 + r] = (f16)acc[h2][nt][i];
            }
    // fused alpha for all 8 heads (head = h2*4 + hl)
#pragma unroll
    for (int h2 = 0; h2 < 2; ++h2) {
        float asv[8], adv[8];
#pragma unroll
        for (int nt = 0; nt < 8; ++nt) {
            asv[nt] = Asrc[h2 * 128 + nt * 16 + r];
            adv[nt] = Adst[h2 * 128 + nt * 16 + r];
        }
#pragma unroll
        for (int i = 0; i < 4; ++i) {
            int gr = bm + r0 + quad * 4 + i;
#pragma unroll
            for (int hl = 0; hl < 4; ++hl) {
                float ps = acc[h2][2 * hl][i] * asv[2 * hl] + acc[h2][2 * hl + 1][i] * asv[2 * hl + 1];
                float pd = acc[h2][2 * hl][i] * adv[2 * hl] + acc[h2][2 * hl + 1][i] * adv[2 * hl + 1];
#pragma unroll
                for (int off = 1; off < 16; off <<= 1) {
                    ps += __shfl_xor(ps, off);
                    pd += __shfl_xor(pd, off);
                }
                if (r == 0 && gr < NNODES) {
                    as1[(size_t)gr * 8 + h2 * 4 + hl] = ps;
                    ad1[(size_t)gr * 8 + h2 * 4 + hl] = pd;
                }
            }
        }
    }
}

// gh[N,32](f16) = h2h @ W2; 64 rows per block; no LDS. Fused: layer-2 alpha dots.
__global__ __launch_bounds__(256) void k_gemm2(const f16* __restrict__ h2h, const f16* __restrict__ W2f,
                                               const float* __restrict__ Asrc, const float* __restrict__ Adst,
                                               f16* __restrict__ gh, float* __restrict__ as2,
                                               float* __restrict__ ad2) {
    int t = threadIdx.x;
    int bm = blockIdx.x * 64;
    int lane = t & 63, w = t >> 6;
    int r = lane & 15, quad = lane >> 4;
    int r0 = w * 16;
    int gra = bm + r0 + r;
    int grac = gra < NNODES ? gra : 0;
    f32x4 acc[2];
    acc[0] = (f32x4){0.f, 0.f, 0.f, 0.f};
    acc[1] = (f32x4){0.f, 0.f, 0.f, 0.f};
#pragma unroll
    for (int kc = 0; kc < 8; ++kc) {
        f16x8 a = *(const f16x8*)(h2h + (size_t)grac * 256 + kc * 32 + quad * 8);
#pragma unroll
        for (int nt = 0; nt < 2; ++nt) {
            f16x8 b = *(const f16x8*)&W2f[(((kc << 5) + nt * 16 + r) * 4 + quad) * 8];
            acc[nt] = __builtin_amdgcn_mfma_f32_16x16x32_f16(a, b, acc[nt], 0, 0, 0);
        }
    }
#pragma unroll
    for (int nt = 0; nt < 2; ++nt)
#pragma unroll
        for (int i = 0; i < 4; ++i) {
            int gr = bm + r0 + quad * 4 + i;
            if (gr < NNODES) gh[(size_t)gr * 32 + nt * 16 + r] = (f16)acc[nt][i];
        }
    float as0 = Asrc[r], as16 = Asrc[16 + r];
    float ad0 = Adst[r], ad16 = Adst[16 + r];
#pragma unroll
    for (int i = 0; i < 4; ++i) {
        int gr = bm + r0 + quad * 4 + i;
        float ps = acc[0][i] * as0 + acc[1][i] * as16;
        float pd = acc[0][i] * ad0 + acc[1][i] * ad16;
#pragma unroll
        for (int off = 1; off < 16; off <<= 1) {
            ps += __shfl_xor(ps, off);
            pd += __shfl_xor(pd, off);
        }
        if (r == 0 && gr < NNODES) { as2[gr] = ps; ad2[gr] = pd; }
    }
}

// ---------------- fused softmax + aggregate ----------------
// No max-subtraction: logits O(1) by construction (validated R6-R12).

// Wave-per-node, 4 nodes/block. Stats pass: gather as1 (L2-resident), write f16
// exp-numerators to eh (CSR-contiguous) + denom sum. s_waitcnt, then main pass:
// f16x8 h1 gather, 2 edge-slots, numerators re-read from L2-hot eh.
__global__ __launch_bounds__(256) void k_agg1(const int* __restrict__ rowst, const unsigned* __restrict__ sd_csr,
                                              const float* __restrict__ as1, const float* __restrict__ ad1,
                                              const f16* __restrict__ h1h, const float* __restrict__ b1,
                                              f16* __restrict__ h2h, f16* __restrict__ eh) {
    int w = threadIdx.x >> 6, lane = threadIdx.x & 63;
    int n = blockIdx.x * 4 + w;
    int s = rowst[n], e = rowst[n + 1];
    // stats: lane = slot8*8 + head8
    int head8 = lane & 7, slot8 = lane >> 3;
    float adn = ad1[(size_t)n * 8 + head8];
    float sum = 0.f;
    for (int j = s + slot8; j < e; j += 8) {
        int src = (int)(sd_csr[j] & 0xffffu);
        float x = as1[(size_t)src * 8 + head8] + adn;
        x = x > 0.f ? x : 0.2f * x;
        float ex = __expf(x);
        eh[(size_t)j * 8 + head8] = (f16)ex;
        sum += ex;
    }
    sum += __shfl_xor(sum, 8);
    sum += __shfl_xor(sum, 16);
    sum += __shfl_xor(sum, 32);
    float inv = 1.f / (sum + 1e-16f);  // lane h (h<8) holds head h's inv
    asm volatile("s_waitcnt vmcnt(0) lgkmcnt(0)" ::: "memory");  // drain stats stores
    // main: slot = lane>>5, ch group c0 = (lane&31)*8, head hm = (lane&31)>>2
    int slot = lane >> 5;
    int ch32 = lane & 31;
    int c0 = ch32 << 3;
    int hm = ch32 >> 2;
    float invq = __shfl(inv, hm);
    const f16* __restrict__ hp = h1h + c0;
    const f16* __restrict__ ep = eh + hm;
    f32x8 acc = (f32x8){0.f, 0.f, 0.f, 0.f, 0.f, 0.f, 0.f, 0.f};
    int j = s + slot;
    for (; j + 6 < e; j += 8) {
        int s0 = (int)(sd_csr[j] & 0xffffu),     s1 = (int)(sd_csr[j + 2] & 0xffffu);
        int s2 = (int)(sd_csr[j + 4] & 0xffffu), s3 = (int)(sd_csr[j + 6] & 0xffffu);
        float a0 = (float)ep[(size_t)j * 8] * invq;
        float a1 = (float)ep[(size_t)(j + 2) * 8] * invq;
        float a2 = (float)ep[(size_t)(j + 4) * 8] * invq;
        float a3 = (float)ep[(size_t)(j + 6) * 8] * invq;
        f16x8 v0 = *(const f16x8*)(hp + (size_t)s0 * 256);
        f16x8 v1 = *(const f16x8*)(hp + (size_t)s1 * 256);
        f16x8 v2 = *(const f16x8*)(hp + (size_t)s2 * 256);
        f16x8 v3 = *(const f16x8*)(hp + (size_t)s3 * 256);
#pragma unroll
        for (int k = 0; k < 8; ++k)
            acc[k] += a0 * (float)v0[k] + a1 * (float)v1[k] + a2 * (float)v2[k] + a3 * (float)v3[k];
    }
    for (; j < e; j += 2) {
        int s0 = (int)(sd_csr[j] & 0xffffu);
        float a0 = (float)ep[(size_t)j * 8] * invq;
        f16x8 v0 = *(const f16x8*)(hp + (size_t)s0 * 256);
#pragma unroll
        for (int k = 0; k < 8; ++k) acc[k] += a0 * (float)v0[k];
    }
#pragma unroll
    for (int k = 0; k < 8; ++k) acc[k] += __shfl_xor(acc[k], 32);
    if (slot == 0) {
        float4 b0 = *(const float4*)(b1 + c0);
        float4 b4 = *(const float4*)(b1 + c0 + 4);
        float o[8] = {acc[0] + b0.x, acc[1] + b0.y, acc[2] + b0.z, acc[3] + b0.w,
                      acc[4] + b4.x, acc[5] + b4.y, acc[6] + b4.z, acc[7] + b4.w};
        f16x8 oh;
#pragma unroll
        for (int k = 0; k < 8; ++k) {
            float v = o[k];
            v = v > 0.f ? v : __expf(v) - 1.f;  // fused ELU
            oh[k] = (f16)v;
        }
        *(f16x8*)(h2h + (size_t)n * 256 + c0) = oh;
    }
}

// Wave-per-node; alpha recomputed from L2-resident as2/ad2 (200 KB); gh f16.
__global__ __launch_bounds__(256) void k_agg2(const int* __restrict__ rowst, const unsigned* __restrict__ sd_csr,
                                              const float* __restrict__ as2, const float* __restrict__ ad2,
                                              const f16* __restrict__ gh, const float* __restrict__ b2,
                                              float* __restrict__ out) {
    int w = threadIdx.x >> 6, lane = threadIdx.x & 63;
    int n = blockIdx.x * 4 + w;
    int s = rowst[n], e = rowst[n + 1];
    float adn = ad2[n];
    float sum = 0.f;
    for (int j = s + lane; j < e; j += 64) {
        float x = as2[(int)(sd_csr[j] & 0xffffu)] + adn;
        x = x > 0.f ? x : 0.2f * x;
        sum += __expf(x);
    }
#pragma unroll
    for (int d = 1; d < 64; d <<= 1) sum += __shfl_xor(sum, d);
    float inv = 1.f / (sum + 1e-16f);
    int slot = lane >> 5, c = lane & 31;
    const f16* __restrict__ gp = gh + c;
    float acc = 0.f;
    for (int j = s + slot; j < e; j += 2) {
        int sn = (int)(sd_csr[j] & 0xffffu);
        float x = as2[sn] + adn;
        x = x > 0.f ? x : 0.2f * x;
        acc += __expf(x) * inv * (float)gp[(size_t)sn * 32];
    }
    acc += __shfl_xor(acc, 32);
    if (slot == 0) out[(size_t)n * 32 + c] = acc + b2[c];
}

// ---------------- launch ----------------

extern "C" void kernel_launch(void* const* d_in, const int* in_sizes, int n_in,
                              void* d_out, int out_size, void* d_ws, size_t ws_size,
                              hipStream_t stream) {
    const float* x    = (const float*)d_in[0];
    const int*   ei   = (const int*)d_in[1];
    const float* W1   = (const float*)d_in[2];
    const float* As1  = (const float*)d_in[3];
    const float* Ad1  = (const float*)d_in[4];
    const float* b1   = (const float*)d_in[5];
    const float* W2   = (const float*)d_in[6];
    const float* As2  = (const float*)d_in[7];
    const float* Ad2  = (const float*)d_in[8];
    const float* b2   = (const float*)d_in[9];
    float* out = (float*)d_out;

    char* p = (char*)d_ws;
    auto alloc = [&](size_t bytes) -> char* {
        char* r = p;
        p += (bytes + 255) & ~(size_t)255;
        return r;
    };
    f16* h1h      = (f16*)alloc((size_t)NNODES * 256 * 2);
    f16* h2h      = (f16*)alloc((size_t)NNODES * 256 * 2);
    f16* W1f      = (f16*)alloc((size_t)128 * 256 * 2);
    f16* W2f      = (f16*)alloc((size_t)256 * 32 * 2);
    f16* gh       = (f16*)alloc((size_t)NNODES * 32 * 2);
    f16* eh       = (f16*)alloc((size_t)NEDGES * 8 * 2);
    float* asrc1  = (float*)alloc((size_t)NNODES * 8 * 4);
    float* adst1  = (float*)alloc((size_t)NNODES * 8 * 4);
    float* asrc2  = (float*)alloc((size_t)NNODES * 4);
    float* adst2  = (float*)alloc((size_t)NNODES * 4);
    int* deg      = (int*)alloc((size_t)NNODES * 4);
    int* incl     = (int*)alloc((size_t)NNODES * 4);
    int* rowst    = (int*)alloc((size_t)(NNODES + 1) * 4);
    int* cursor   = (int*)alloc((size_t)NNODES * 4);
    unsigned* sdc = (unsigned*)alloc((size_t)NEDGES * 4);
    int* partial  = (int*)alloc(256 * 4);

    const int EB = NEDGES / 256;           // 3125
    const int NCH = (NNODES + 255) / 256;  // 196

    hipMemsetAsync(deg, 0, (size_t)NNODES * 4, stream);
    k_deg_wfrag<<<EB + 160, 256, 0, stream>>>(ei, deg, W1, W2, W1f, W2f);
    k_scanA<<<NCH, 256, 0, stream>>>(deg, incl, partial);
    k_scanC<<<NCH, 256, 0, stream>>>(deg, incl, partial, rowst, cursor);
    k_scatter<<<EB, 256, 0, stream>>>(ei, cursor, sdc);

    k_gemm1_sc<<<GB, 256, 0, stream>>>(x, W1f, As1, Ad1, h1h, asrc1, adst1, ei, cursor, sdc);
    k_agg1<<<NNODES / 4, 256, 0, stream>>>(rowst, sdc, asrc1, adst1, h1h, b1, h2h, eh);

    k_gemm2<<<(NNODES + 63) / 64, 256, 0, stream>>>(h2h, W2f, As2, Ad2, gh, asrc2, adst2);
    k_agg2<<<NNODES / 4, 256, 0, stream>>>(rowst, sdc, asrc2, adst2, gh, b2, out);
}

// Round 16
// 299.696 us; speedup vs baseline: 1.1481x; 1.1481x over previous
//
#include <hip/hip_runtime.h>
#include <math.h>

#define NNODES 50000
#define NEDGES 800000
#define GB 782  // gemm1 row-blocks = (NNODES+63)/64

typedef _Float16 f16;
typedef _Float16 f16x8 __attribute__((ext_vector_type(8)));
typedef _Float16 f16x4 __attribute__((ext_vector_type(4)));
typedef float f32x4 __attribute__((ext_vector_type(4)));
typedef float f32x8 __attribute__((ext_vector_type(8)));

// ---------------- CSR build + weight pack ----------------

// blocks [0,3125): degree histogram + per-edge rank (atomic return value);
// blocks [3125,3285): weight fragment pack
__global__ __launch_bounds__(256) void k_deg_wfrag(const int* __restrict__ ei, int* __restrict__ deg,
                                                   int* __restrict__ rank,
                                                   const float* __restrict__ W1, const float* __restrict__ W2,
                                                   f16* __restrict__ W1f, f16* __restrict__ W2f) {
    int bid = blockIdx.x;
    if (bid < NEDGES / 256) {
        int e = bid * 256 + threadIdx.x;
        rank[e] = atomicAdd(&deg[ei[NEDGES + e]], 1);
    } else {
        int id = (bid - NEDGES / 256) * 256 + threadIdx.x;
        if (id < 32768) {  // W1: 128 x 256
            int k = id >> 8, c = id & 255;
            int kc = k >> 5, quad = (k & 31) >> 3, j = k & 7;
            W1f[(((kc << 8) + c) * 4 + quad) * 8 + j] = (f16)W1[id];
        } else {           // W2: 256 x 32
            int i2 = id - 32768;
            int k = i2 >> 5, c = i2 & 31;
            int kc = k >> 5, quad = (k & 31) >> 3, j = k & 7;
            W2f[(((kc << 5) + c) * 4 + quad) * 8 + j] = (f16)W2[i2];
        }
    }
}

__global__ __launch_bounds__(256) void k_scanA(const int* __restrict__ deg, int* __restrict__ incl,
                                               int* __restrict__ partial) {
    int t = threadIdx.x;
    int i = blockIdx.x * 256 + t;
    int v = (i < NNODES) ? deg[i] : 0;
    int lane = t & 63, wid = t >> 6;
    int s = v;
#pragma unroll
    for (int d = 1; d < 64; d <<= 1) { int u = __shfl_up(s, d, 64); if (lane >= d) s += u; }
    __shared__ int wtot[4];
    if (lane == 63) wtot[wid] = s;
    __syncthreads();
    int off = 0;
    for (int w = 0; w < wid; ++w) off += wtot[w];
    s += off;
    if (i < NNODES) incl[i] = s;
    if (t == 255) partial[blockIdx.x] = s;
}

__global__ __launch_bounds__(256) void k_scanC(const int* __restrict__ deg, const int* __restrict__ incl,
                                               const int* __restrict__ partial, int* __restrict__ rowst) {
    int t = threadIdx.x, bid = blockIdx.x;
    int v = (t < bid) ? partial[t] : 0;  // bid <= 195 < 256
    int lane = t & 63, wid = t >> 6;
#pragma unroll
    for (int d = 1; d < 64; d <<= 1) v += __shfl_xor(v, d);
    __shared__ int ws[4];
    if (lane == 0) ws[wid] = v;
    __syncthreads();
    int choff = ws[0] + ws[1] + ws[2] + ws[3];
    int i = bid * 256 + t;
    if (i < NNODES) {
        int rs1 = incl[i] + choff;
        rowst[i + 1] = rs1;
        if (i == 0) rowst[0] = 0;
    }
}

// ---------------- gemm1 + atomic-free thin scatter (merged grid) ----------------
// mfma_f32_16x16x32_f16 (lane=tid&63, r=lane&15, quad=lane>>4):
//   A frag a[j]=A[r][quad*8+j]  B frag b[j]=B[quad*8+j][r]  D d[i]=D[quad*4+i][r]
// Blocks [0,GB): h1h = X @ W1 (64 rows x 256 cols) + fused alpha dots.
// Blocks [GB,GB+3125): scatter sd_csr[rowst[d]+rank[e]] = (d<<16)|s — no atomic,
// fire-and-forget stores pipeline at throughput; overlaps the MFMA blocks.

__global__ __launch_bounds__(256) void k_gemm1_sc(const float* __restrict__ X, const f16* __restrict__ W1f,
                                                  const float* __restrict__ Asrc, const float* __restrict__ Adst,
                                                  f16* __restrict__ h1h, float* __restrict__ as1,
                                                  float* __restrict__ ad1, const int* __restrict__ ei,
                                                  const int* __restrict__ rowst, const int* __restrict__ rank,
                                                  unsigned* __restrict__ sd_csr) {
    __shared__ f16 sA[64 * 136];
    int bid = blockIdx.x;
    int t = threadIdx.x;
    if (bid >= GB) {  // scatter path (uniform per block)
        int e = (bid - GB) * 256 + t;
        if (e < NEDGES) {
            int s = ei[e], d = ei[NEDGES + e];
            int pos = rowst[d] + rank[e];
            sd_csr[pos] = ((unsigned)d << 16) | (unsigned)s;
        }
        return;
    }
    int bm = bid * 64;
#pragma unroll
    for (int i = 0; i < 8; ++i) {
        int idx = i * 256 + t;
        int row = idx >> 5, c4 = (idx & 31) << 2;
        int gr = bm + row;
        float4 v = make_float4(0.f, 0.f, 0.f, 0.f);
        if (gr < NNODES) v = *(const float4*)(X + (size_t)gr * 128 + c4);
        f16x4 h = {(f16)v.x, (f16)v.y, (f16)v.z, (f16)v.w};
        *(f16x4*)&sA[row * 136 + c4] = h;
    }
    __syncthreads();
    int lane = t & 63, w = t >> 6;
    int r = lane & 15, quad = lane >> 4;
    int r0 = w * 16;
    f32x4 acc[2][8];
#pragma unroll
    for (int h2 = 0; h2 < 2; ++h2)
#pragma unroll
        for (int nt = 0; nt < 8; ++nt) acc[h2][nt] = (f32x4){0.f, 0.f, 0.f, 0.f};
#pragma unroll
    for (int kc = 0; kc < 4; ++kc) {
        f16x8 a = *(f16x8*)&sA[(r0 + r) * 136 + kc * 32 + quad * 8];
#pragma unroll
        for (int h2 = 0; h2 < 2; ++h2)
#pragma unroll
            for (int nt = 0; nt < 8; ++nt) {
                f16x8 b = *(const f16x8*)&W1f[(((kc << 8) + h2 * 128 + nt * 16 + r) * 4 + quad) * 8];
                acc[h2][nt] = __builtin_amdgcn_mfma_f32_16x16x32_f16(a, b, acc[h2][nt], 0, 0, 0);
            }
    }
#pragma unroll
    for (int h2 = 0; h2 < 2; ++h2)
#pragma unroll
        for (int nt = 0; nt < 8; ++nt)
#pragma unroll
            for (int i = 0; i < 4; ++i) {
                int gr = bm + r0 + quad * 4 + i;
                if (gr < NNODES) h1h[(size_t)gr * 256 + h2 * 128 + nt * 16 + r] = (f16)acc[h2][nt][i];
            }
    // fused alpha for all 8 heads (head = h2*4 + hl)
#pragma unroll
    for (int h2 = 0; h2 < 2; ++h2) {
        float asv[8], adv[8];
#pragma unroll
        for (int nt = 0; nt < 8; ++nt) {
            asv[nt] = Asrc[h2 * 128 + nt * 16 + r];
            adv[nt] = Adst[h2 * 128 + nt * 16 + r];
        }
#pragma unroll
        for (int i = 0; i < 4; ++i) {
            int gr = bm + r0 + quad * 4 + i;
#pragma unroll
            for (int hl = 0; hl < 4; ++hl) {
                float ps = acc[h2][2 * hl][i] * asv[2 * hl] + acc[h2][2 * hl + 1][i] * asv[2 * hl + 1];
                float pd = acc[h2][2 * hl][i] * adv[2 * hl] + acc[h2][2 * hl + 1][i] * adv[2 * hl + 1];
#pragma unroll
                for (int off = 1; off < 16; off <<= 1) {
                    ps += __shfl_xor(ps, off);
                    pd += __shfl_xor(pd, off);
                }
                if (r == 0 && gr < NNODES) {
                    as1[(size_t)gr * 8 + h2 * 4 + hl] = ps;
                    ad1[(size_t)gr * 8 + h2 * 4 + hl] = pd;
                }
            }
        }
    }
}

// gh[N,32](f16) = h2h @ W2; 64 rows per block; no LDS. Fused: layer-2 alpha dots.
__global__ __launch_bounds__(256) void k_gemm2(const f16* __restrict__ h2h, const f16* __restrict__ W2f,
                                               const float* __restrict__ Asrc, const float* __restrict__ Adst,
                                               f16* __restrict__ gh, float* __restrict__ as2,
                                               float* __restrict__ ad2) {
    int t = threadIdx.x;
    int bm = blockIdx.x * 64;
    int lane = t & 63, w = t >> 6;
    int r = lane & 15, quad = lane >> 4;
    int r0 = w * 16;
    int gra = bm + r0 + r;
    int grac = gra < NNODES ? gra : 0;
    f32x4 acc[2];
    acc[0] = (f32x4){0.f, 0.f, 0.f, 0.f};
    acc[1] = (f32x4){0.f, 0.f, 0.f, 0.f};
#pragma unroll
    for (int kc = 0; kc < 8; ++kc) {
        f16x8 a = *(const f16x8*)(h2h + (size_t)grac * 256 + kc * 32 + quad * 8);
#pragma unroll
        for (int nt = 0; nt < 2; ++nt) {
            f16x8 b = *(const f16x8*)&W2f[(((kc << 5) + nt * 16 + r) * 4 + quad) * 8];
            acc[nt] = __builtin_amdgcn_mfma_f32_16x16x32_f16(a, b, acc[nt], 0, 0, 0);
        }
    }
#pragma unroll
    for (int nt = 0; nt < 2; ++nt)
#pragma unroll
        for (int i = 0; i < 4; ++i) {
            int gr = bm + r0 + quad * 4 + i;
            if (gr < NNODES) gh[(size_t)gr * 32 + nt * 16 + r] = (f16)acc[nt][i];
        }
    float as0 = Asrc[r], as16 = Asrc[16 + r];
    float ad0 = Adst[r], ad16 = Adst[16 + r];
#pragma unroll
    for (int i = 0; i < 4; ++i) {
        int gr = bm + r0 + quad * 4 + i;
        float ps = acc[0][i] * as0 + acc[1][i] * as16;
        float pd = acc[0][i] * ad0 + acc[1][i] * ad16;
#pragma unroll
        for (int off = 1; off < 16; off <<= 1) {
            ps += __shfl_xor(ps, off);
            pd += __shfl_xor(pd, off);
        }
        if (r == 0 && gr < NNODES) { as2[gr] = ps; ad2[gr] = pd; }
    }
}

// ---------------- fused softmax + aggregate ----------------
// No max-subtraction: logits O(1) by construction (validated R6-R15).

// Wave-per-node, 4 nodes/block. Stats pass: gather as1 (L2-resident), write f16
// exp-numerators to eh (CSR-contiguous) + denom sum. s_waitcnt, then main pass:
// f16x8 h1 gather, 2 edge-slots, numerators re-read from L2-hot eh.
__global__ __launch_bounds__(256) void k_agg1(const int* __restrict__ rowst, const unsigned* __restrict__ sd_csr,
                                              const float* __restrict__ as1, const float* __restrict__ ad1,
                                              const f16* __restrict__ h1h, const float* __restrict__ b1,
                                              f16* __restrict__ h2h, f16* __restrict__ eh) {
    int w = threadIdx.x >> 6, lane = threadIdx.x & 63;
    int n = blockIdx.x * 4 + w;
    int s = rowst[n], e = rowst[n + 1];
    // stats: lane = slot8*8 + head8
    int head8 = lane & 7, slot8 = lane >> 3;
    float adn = ad1[(size_t)n * 8 + head8];
    float sum = 0.f;
    for (int j = s + slot8; j < e; j += 8) {
        int src = (int)(sd_csr[j] & 0xffffu);
        float x = as1[(size_t)src * 8 + head8] + adn;
        x = x > 0.f ? x : 0.2f * x;
        float ex = __expf(x);
        eh[(size_t)j * 8 + head8] = (f16)ex;
        sum += ex;
    }
    sum += __shfl_xor(sum, 8);
    sum += __shfl_xor(sum, 16);
    sum += __shfl_xor(sum, 32);
    float inv = 1.f / (sum + 1e-16f);  // lane h (h<8) holds head h's inv
    asm volatile("s_waitcnt vmcnt(0) lgkmcnt(0)" ::: "memory");  // drain stats stores
    // main: slot = lane>>5, ch group c0 = (lane&31)*8, head hm = (lane&31)>>2
    int slot = lane >> 5;
    int ch32 = lane & 31;
    int c0 = ch32 << 3;
    int hm = ch32 >> 2;
    float invq = __shfl(inv, hm);
    const f16* __restrict__ hp = h1h + c0;
    const f16* __restrict__ ep = eh + hm;
    f32x8 acc = (f32x8){0.f, 0.f, 0.f, 0.f, 0.f, 0.f, 0.f, 0.f};
    int j = s + slot;
    for (; j + 6 < e; j += 8) {
        int s0 = (int)(sd_csr[j] & 0xffffu),     s1 = (int)(sd_csr[j + 2] & 0xffffu);
        int s2 = (int)(sd_csr[j + 4] & 0xffffu), s3 = (int)(sd_csr[j + 6] & 0xffffu);
        float a0 = (float)ep[(size_t)j * 8] * invq;
        float a1 = (float)ep[(size_t)(j + 2) * 8] * invq;
        float a2 = (float)ep[(size_t)(j + 4) * 8] * invq;
        float a3 = (float)ep[(size_t)(j + 6) * 8] * invq;
        f16x8 v0 = *(const f16x8*)(hp + (size_t)s0 * 256);
        f16x8 v1 = *(const f16x8*)(hp + (size_t)s1 * 256);
        f16x8 v2 = *(const f16x8*)(hp + (size_t)s2 * 256);
        f16x8 v3 = *(const f16x8*)(hp + (size_t)s3 * 256);
#pragma unroll
        for (int k = 0; k < 8; ++k)
            acc[k] += a0 * (float)v0[k] + a1 * (float)v1[k] + a2 * (float)v2[k] + a3 * (float)v3[k];
    }
    for (; j < e; j += 2) {
        int s0 = (int)(sd_csr[j] & 0xffffu);
        float a0 = (float)ep[(size_t)j * 8] * invq;
        f16x8 v0 = *(const f16x8*)(hp + (size_t)s0 * 256);
#pragma unroll
        for (int k = 0; k < 8; ++k) acc[k] += a0 * (float)v0[k];
    }
#pragma unroll
    for (int k = 0; k < 8; ++k) acc[k] += __shfl_xor(acc[k], 32);
    if (slot == 0) {
        float4 b0 = *(const float4*)(b1 + c0);
        float4 b4 = *(const float4*)(b1 + c0 + 4);
        float o[8] = {acc[0] + b0.x, acc[1] + b0.y, acc[2] + b0.z, acc[3] + b0.w,
                      acc[4] + b4.x, acc[5] + b4.y, acc[6] + b4.z, acc[7] + b4.w};
        f16x8 oh;
#pragma unroll
        for (int k = 0; k < 8; ++k) {
            float v = o[k];
            v = v > 0.f ? v : __expf(v) - 1.f;  // fused ELU
            oh[k] = (f16)v;
        }
        *(f16x8*)(h2h + (size_t)n * 256 + c0) = oh;
    }
}

// Wave-per-node; alpha recomputed from L2-resident as2/ad2 (200 KB); gh f16.
__global__ __launch_bounds__(256) void k_agg2(const int* __restrict__ rowst, const unsigned* __restrict__ sd_csr,
                                              const float* __restrict__ as2, const float* __restrict__ ad2,
                                              const f16* __restrict__ gh, const float* __restrict__ b2,
                                              float* __restrict__ out) {
    int w = threadIdx.x >> 6, lane = threadIdx.x & 63;
    int n = blockIdx.x * 4 + w;
    int s = rowst[n], e = rowst[n + 1];
    float adn = ad2[n];
    float sum = 0.f;
    for (int j = s + lane; j < e; j += 64) {
        float x = as2[(int)(sd_csr[j] & 0xffffu)] + adn;
        x = x > 0.f ? x : 0.2f * x;
        sum += __expf(x);
    }
#pragma unroll
    for (int d = 1; d < 64; d <<= 1) sum += __shfl_xor(sum, d);
    float inv = 1.f / (sum + 1e-16f);
    int slot = lane >> 5, c = lane & 31;
    const f16* __restrict__ gp = gh + c;
    float acc = 0.f;
    for (int j = s + slot; j < e; j += 2) {
        int sn = (int)(sd_csr[j] & 0xffffu);
        float x = as2[sn] + adn;
        x = x > 0.f ? x : 0.2f * x;
        acc += __expf(x) * inv * (float)gp[(size_t)sn * 32];
    }
    acc += __shfl_xor(acc, 32);
    if (slot == 0) out[(size_t)n * 32 + c] = acc + b2[c];
}

// ---------------- launch ----------------

extern "C" void kernel_launch(void* const* d_in, const int* in_sizes, int n_in,
                              void* d_out, int out_size, void* d_ws, size_t ws_size,
                              hipStream_t stream) {
    const float* x    = (const float*)d_in[0];
    const int*   ei   = (const int*)d_in[1];
    const float* W1   = (const float*)d_in[2];
    const float* As1  = (const float*)d_in[3];
    const float* Ad1  = (const float*)d_in[4];
    const float* b1   = (const float*)d_in[5];
    const float* W2   = (const float*)d_in[6];
    const float* As2  = (const float*)d_in[7];
    const float* Ad2  = (const float*)d_in[8];
    const float* b2   = (const float*)d_in[9];
    float* out = (float*)d_out;

    char* p = (char*)d_ws;
    auto alloc = [&](size_t bytes) -> char* {
        char* r = p;
        p += (bytes + 255) & ~(size_t)255;
        return r;
    };
    f16* h1h      = (f16*)alloc((size_t)NNODES * 256 * 2);
    f16* h2h      = (f16*)alloc((size_t)NNODES * 256 * 2);
    f16* W1f      = (f16*)alloc((size_t)128 * 256 * 2);
    f16* W2f      = (f16*)alloc((size_t)256 * 32 * 2);
    f16* gh       = (f16*)alloc((size_t)NNODES * 32 * 2);
    f16* eh       = (f16*)alloc((size_t)NEDGES * 8 * 2);
    float* asrc1  = (float*)alloc((size_t)NNODES * 8 * 4);
    float* adst1  = (float*)alloc((size_t)NNODES * 8 * 4);
    float* asrc2  = (float*)alloc((size_t)NNODES * 4);
    float* adst2  = (float*)alloc((size_t)NNODES * 4);
    int* deg      = (int*)alloc((size_t)NNODES * 4);
    int* incl     = (int*)alloc((size_t)NNODES * 4);
    int* rowst    = (int*)alloc((size_t)(NNODES + 1) * 4);
    int* rank     = (int*)alloc((size_t)NEDGES * 4);
    unsigned* sdc = (unsigned*)alloc((size_t)NEDGES * 4);
    int* partial  = (int*)alloc(256 * 4);

    const int EB = NEDGES / 256;           // 3125
    const int NCH = (NNODES + 255) / 256;  // 196

    hipMemsetAsync(deg, 0, (size_t)NNODES * 4, stream);
    k_deg_wfrag<<<EB + 160, 256, 0, stream>>>(ei, deg, rank, W1, W2, W1f, W2f);
    k_scanA<<<NCH, 256, 0, stream>>>(deg, incl, partial);
    k_scanC<<<NCH, 256, 0, stream>>>(deg, incl, partial, rowst);

    k_gemm1_sc<<<GB + EB, 256, 0, stream>>>(x, W1f, As1, Ad1, h1h, asrc1, adst1, ei, rowst, rank, sdc);
    k_agg1<<<NNODES / 4, 256, 0, stream>>>(rowst, sdc, asrc1, adst1, h1h, b1, h2h, eh);

    k_gemm2<<<(NNODES + 63) / 64, 256, 0, stream>>>(h2h, W2f, As2, Ad2, gh, asrc2, adst2);
    k_agg2<<<NNODES / 4, 256, 0, stream>>>(rowst, sdc, asrc2, adst2, gh, b2, out);
}